// Round 5
// baseline (145.746 us; speedup 1.0000x reference)
//
#include <hip/hip_runtime.h>

#define NGAUSS 2048
#define NPIX   65536
#define WID    512.0f
#define HEI    512.0f
#define NSLICE 32                 // gaussian split across blocks
#define GPB    (NGAUSS / NSLICE)  // 64 gaussians per block
#define TPB    512                // threads per block
#define PPT    8                  // pixels per thread (4 packed v2f pairs)
#define PPB    (TPB * PPT)        // 4096 pixels per block
#define NPG    (NPIX / PPB)       // 16 pixel groups

typedef float v2f __attribute__((ext_vector_type(2)));

// SoA coefficient arrays (NOT duplicated — v_pk_fma_f32 op_sel splats a
// scalar half into both result halves for free):
//   PA[n] = (A, B, C, D)   PB[n] = (E0, E1, r, g)   PC[n] = b
// dx = A*X + B*Y + E0 ; dy = C*X + D*Y + E1 ; w = exp2(-(dx^2+dy^2))
// A..E pre-scaled by sqrt(log2(e)) so exp(-q) == exp2(-q_scaled).

static __device__ __forceinline__ v2f splat(float s) { return (v2f){s, s}; }

__global__ __launch_bounds__(256) void prep_kernel(
    const float* __restrict__ rgb, const float* __restrict__ mu,
    const float* __restrict__ scale, const float* __restrict__ angle,
    float4* __restrict__ PA, float4* __restrict__ PB, float* __restrict__ PC)
{
    int n = blockIdx.x * blockDim.x + threadIdx.x;
    if (n >= NGAUSS) return;
    const float MU_BORDER = 1.05f;
    const float S_MIN = 1.0f / 30.0f;
    const float S_MAX = 1.0f / 0.75f;
    const float PI_APPROX = 3.1416f;
    const float K = 1.2011224087864498f;  // sqrt(log2(e))

    float mx = tanhf(mu[2*n+0]) * MU_BORDER * (0.5f * WID);
    float my = tanhf(mu[2*n+1]) * MU_BORDER * (0.5f * HEI);
    float al = tanhf(angle[n]) * PI_APPROX;
    float c = cosf(al);
    float s = sinf(al);
    float S0 = 1.0f / (1.0f + expf(-scale[2*n+0])) * (S_MAX - S_MIN) + S_MIN;
    float S1 = 1.0f / (1.0f + expf(-scale[2*n+1])) * (S_MAX - S_MIN) + S_MIN;

    float A  =  S0 * c * K;
    float Bc = -(S0 * s * K);
    float C  =  S1 * s * K;
    float D  =  S1 * c * K;
    float E0 = -(A * mx + Bc * my);
    float E1 = -(C * mx + D  * my);

    float r = 1.0f / (1.0f + expf(-rgb[3*n+0]));
    float g = 1.0f / (1.0f + expf(-rgb[3*n+1]));
    float b = 1.0f / (1.0f + expf(-rgb[3*n+2]));

    PA[n] = make_float4(A, Bc, C, D);
    PB[n] = make_float4(E0, E1, r, g);
    PC[n] = b;
}

__global__ __launch_bounds__(TPB, 4) void splat_kernel(
    const float2* __restrict__ x, const float4* __restrict__ PA,
    const float4* __restrict__ PB, const float* __restrict__ PC,
    float* __restrict__ out)
{
    __shared__ float4 smA[GPB];   // 1 KiB
    __shared__ float4 smB[GPB];   // 1 KiB
    __shared__ float  smC[GPB];   // 256 B

    // slice in HIGH bits: the 32 slices of a pg are 16-apart in blockIdx
    // -> same XCD under %8 round-robin -> atomic lines stay in one L2.
    const int pg    = blockIdx.x & (NPG - 1);
    const int slice = blockIdx.x >> 4;
    const int tid   = threadIdx.x;

    if (tid < GPB) {
        smA[tid] = PA[slice * GPB + tid];
        smB[tid] = PB[slice * GPB + tid];
        smC[tid] = PC[slice * GPB + tid];
    }

    // 8 pixels per thread: base + k*TPB, packed as 4 (v2f) pairs
    const int base = pg * PPB + tid;
    v2f PX[4], PY[4];
    #pragma unroll
    for (int k = 0; k < 4; ++k) {
        float2 a = x[base + (2*k+0) * TPB];
        float2 b = x[base + (2*k+1) * TPB];
        PX[k] = (v2f){a.x - 0.5f * WID, b.x - 0.5f * WID};
        PY[k] = (v2f){a.y - 0.5f * HEI, b.y - 0.5f * HEI};
    }

    __syncthreads();

    v2f ar[4], ag[4], ab[4];
    #pragma unroll
    for (int k = 0; k < 4; ++k) { ar[k] = (v2f){0.f,0.f}; ag[k] = (v2f){0.f,0.f}; ab[k] = (v2f){0.f,0.f}; }

    #pragma unroll 4
    for (int j = 0; j < GPB; ++j) {
        float4 c0 = smA[j];   // A,B,C,D   (wave-uniform broadcast reads)
        float4 c1 = smB[j];   // E0,E1,r,g
        float  cb = smC[j];   // b
        v2f A  = splat(c0.x), Bc = splat(c0.y), C = splat(c0.z), D = splat(c0.w);
        v2f E0 = splat(c1.x), E1 = splat(c1.y);
        v2f cr = splat(c1.z), cg = splat(c1.w), cbl = splat(cb);
        #pragma unroll
        for (int k = 0; k < 4; ++k) {
            v2f dx = __builtin_elementwise_fma(A, PX[k],
                       __builtin_elementwise_fma(Bc, PY[k], E0));
            v2f dy = __builtin_elementwise_fma(C, PX[k],
                       __builtin_elementwise_fma(D, PY[k], E1));
            v2f q  = __builtin_elementwise_fma(dx, dx, dy * dy);
            v2f w;
            w.x = __builtin_amdgcn_exp2f(-q.x);
            w.y = __builtin_amdgcn_exp2f(-q.y);
            ar[k] = __builtin_elementwise_fma(w, cr, ar[k]);
            ag[k] = __builtin_elementwise_fma(w, cg, ag[k]);
            ab[k] = __builtin_elementwise_fma(w, cbl, ab[k]);
        }
    }

    #pragma unroll
    for (int k = 0; k < 4; ++k) {
        int p0 = base + (2*k+0) * TPB;
        int p1 = base + (2*k+1) * TPB;
        atomicAdd(&out[3*p0 + 0], ar[k].x);
        atomicAdd(&out[3*p0 + 1], ag[k].x);
        atomicAdd(&out[3*p0 + 2], ab[k].x);
        atomicAdd(&out[3*p1 + 0], ar[k].y);
        atomicAdd(&out[3*p1 + 1], ag[k].y);
        atomicAdd(&out[3*p1 + 2], ab[k].y);
    }
}

extern "C" void kernel_launch(void* const* d_in, const int* in_sizes, int n_in,
                              void* d_out, int out_size, void* d_ws, size_t ws_size,
                              hipStream_t stream) {
    const float* x     = (const float*)d_in[0];  // [B,2]
    const float* rgb   = (const float*)d_in[1];  // [N,3]
    const float* mu    = (const float*)d_in[2];  // [N,2]
    const float* scale = (const float*)d_in[3];  // [N,2]
    const float* angle = (const float*)d_in[4];  // [N]

    float4* PA = (float4*)d_ws;                               // 32 KiB
    float4* PB = (float4*)((char*)d_ws + NGAUSS * 16);        // 32 KiB
    float*  PC = (float*)((char*)d_ws + NGAUSS * 32);         // 8 KiB

    hipMemsetAsync(d_out, 0, (size_t)out_size * sizeof(float), stream);

    hipLaunchKernelGGL(prep_kernel, dim3(NGAUSS / 256), dim3(256), 0, stream,
                       rgb, mu, scale, angle, PA, PB, PC);
    hipLaunchKernelGGL(splat_kernel, dim3(NSLICE * NPG), dim3(TPB), 0, stream,
                       (const float2*)x, PA, PB, PC, (float*)d_out);
}

// Round 6
// 110.793 us; speedup vs baseline: 1.3155x; 1.3155x over previous
//
#include <hip/hip_runtime.h>

#define NGAUSS 2048
#define NPIX   65536
#define WID    512.0f
#define HEI    512.0f
#define TPB    1024               // 16 waves per block
#define NWAVE  16
#define GPW    (NGAUSS / NWAVE)   // 128 gaussians per wave (N split in-block)
#define PPB    128                // pixels per block: 64 lanes x 2 packed
#define NBLK   (NPIX / PPB)       // 512 blocks = 2 blocks/CU = 32 waves/CU

typedef float v2f __attribute__((ext_vector_type(2)));

// One kernel, one dispatch. Block covers ALL gaussians for its 128 pixels:
//  - fused prep: 2 gaussians/thread -> LDS SoA (smA/smB/smC, 73.5 KiB)
//  - wave w accumulates gaussians [128w, 128w+128) for the SAME 128 pixels
//  - in-block reduction via ds_add_f32 (96 wave-instrs), plain coalesced store
// No global atomics (R5 showed ~12 B HBM write per atomicAdd), no memset,
// no workspace, no second kernel.
// dx = A*X + B*Y + E0 ; dy = C*X + D*Y + E1 ; w = exp2(-(dx^2+dy^2))
// A..E pre-scaled by sqrt(log2(e)) so exp(-q) == exp2(-q_scaled).

static __device__ __forceinline__ v2f splat2(float s) { return (v2f){s, s}; }

__global__ __launch_bounds__(TPB, 8) void splat_kernel(
    const float2* __restrict__ x, const float* __restrict__ rgb,
    const float* __restrict__ mu, const float* __restrict__ scale,
    const float* __restrict__ angle, float* __restrict__ out)
{
    __shared__ float4 smA[NGAUSS];     // (A,B,C,D)      32 KiB
    __shared__ float4 smB[NGAUSS];     // (E0,E1,r,g)    32 KiB
    __shared__ float  smC[NGAUSS];     // b               8 KiB
    __shared__ float  smOut[PPB * 3];  // reduction      1.5 KiB

    const int tid = threadIdx.x;

    // ---- fused prep: 2 gaussians per thread ----
    #pragma unroll
    for (int n = tid; n < NGAUSS; n += TPB) {
        const float MU_BORDER = 1.05f;
        const float S_MIN = 1.0f / 30.0f;
        const float S_MAX = 1.0f / 0.75f;
        const float PI_APPROX = 3.1416f;
        const float K = 1.2011224087864498f;  // sqrt(log2(e))

        float mx = tanhf(mu[2*n+0]) * MU_BORDER * (0.5f * WID);
        float my = tanhf(mu[2*n+1]) * MU_BORDER * (0.5f * HEI);
        float al = tanhf(angle[n]) * PI_APPROX;
        float c = cosf(al);
        float s = sinf(al);
        float S0 = 1.0f / (1.0f + expf(-scale[2*n+0])) * (S_MAX - S_MIN) + S_MIN;
        float S1 = 1.0f / (1.0f + expf(-scale[2*n+1])) * (S_MAX - S_MIN) + S_MIN;

        float A  =  S0 * c * K;
        float Bc = -(S0 * s * K);
        float C  =  S1 * s * K;
        float D  =  S1 * c * K;
        float E0 = -(A * mx + Bc * my);
        float E1 = -(C * mx + D  * my);

        float r = 1.0f / (1.0f + expf(-rgb[3*n+0]));
        float g = 1.0f / (1.0f + expf(-rgb[3*n+1]));
        float b = 1.0f / (1.0f + expf(-rgb[3*n+2]));

        smA[n] = make_float4(A, Bc, C, D);
        smB[n] = make_float4(E0, E1, r, g);
        smC[n] = b;
    }
    if (tid < PPB * 3) smOut[tid] = 0.f;

    // ---- pixel load: every wave handles the same 128 pixels, 2/lane ----
    const int lane   = tid & 63;
    const int pxbase = blockIdx.x * PPB;
    float2 a = x[pxbase + lane];
    float2 b = x[pxbase + 64 + lane];
    v2f PX = {a.x - 0.5f * WID, b.x - 0.5f * WID};
    v2f PY = {a.y - 0.5f * HEI, b.y - 0.5f * HEI};

    __syncthreads();

    // ---- main loop: this wave's 128-gaussian slice (broadcast LDS reads) ----
    const int gbase = (tid >> 6) * GPW;
    v2f ar = {0.f, 0.f}, ag = {0.f, 0.f}, ab = {0.f, 0.f};
    #pragma unroll 4
    for (int j = 0; j < GPW; ++j) {
        float4 c0 = smA[gbase + j];   // A,B,C,D
        float4 c1 = smB[gbase + j];   // E0,E1,r,g
        float  cb = smC[gbase + j];   // b
        v2f dx = __builtin_elementwise_fma(splat2(c0.x), PX,
                   __builtin_elementwise_fma(splat2(c0.y), PY, splat2(c1.x)));
        v2f dy = __builtin_elementwise_fma(splat2(c0.z), PX,
                   __builtin_elementwise_fma(splat2(c0.w), PY, splat2(c1.y)));
        v2f q  = __builtin_elementwise_fma(dx, dx, dy * dy);
        v2f w;
        w.x = __builtin_amdgcn_exp2f(-q.x);
        w.y = __builtin_amdgcn_exp2f(-q.y);
        ar = __builtin_elementwise_fma(w, splat2(c1.z), ar);
        ag = __builtin_elementwise_fma(w, splat2(c1.w), ag);
        ab = __builtin_elementwise_fma(w, splat2(cb),   ab);
    }

    // ---- in-block reduction across the 16 wave-slices (LDS f32 atomics) ----
    atomicAdd(&smOut[3*lane + 0],        ar.x);
    atomicAdd(&smOut[3*lane + 1],        ag.x);
    atomicAdd(&smOut[3*lane + 2],        ab.x);
    atomicAdd(&smOut[3*(64 + lane) + 0], ar.y);
    atomicAdd(&smOut[3*(64 + lane) + 1], ag.y);
    atomicAdd(&smOut[3*(64 + lane) + 2], ab.y);
    __syncthreads();

    // ---- coalesced store: 384 floats = out[pxbase..pxbase+128)[3] ----
    if (tid < PPB * 3) out[pxbase * 3 + tid] = smOut[tid];
}

extern "C" void kernel_launch(void* const* d_in, const int* in_sizes, int n_in,
                              void* d_out, int out_size, void* d_ws, size_t ws_size,
                              hipStream_t stream) {
    const float* x     = (const float*)d_in[0];  // [B,2]
    const float* rgb   = (const float*)d_in[1];  // [N,3]
    const float* mu    = (const float*)d_in[2];  // [N,2]
    const float* scale = (const float*)d_in[3];  // [N,2]
    const float* angle = (const float*)d_in[4];  // [N]

    hipLaunchKernelGGL(splat_kernel, dim3(NBLK), dim3(TPB), 0, stream,
                       (const float2*)x, rgb, mu, scale, angle, (float*)d_out);
}